// Round 2
// baseline (23437.927 us; speedup 1.0000x reference)
//
#include <hip/hip_runtime.h>

typedef __attribute__((ext_vector_type(8))) short bf16x8;
typedef __attribute__((ext_vector_type(4))) float f32x4;

#define NBLK 256

// ---------- helpers ----------
__device__ __forceinline__ unsigned short f2bf(float f) {
  unsigned u = __float_as_uint(f);
  unsigned r = u + 0x7fffu + ((u >> 16) & 1u);   // RNE
  return (unsigned short)(r >> 16);
}
__device__ __forceinline__ float bf2f(unsigned short h) {
  return __uint_as_float(((unsigned)h) << 16);
}
// packed = (hi_bits<<16) | lo_bits ; hi+lo reconstructs f to ~2^-16 rel
__device__ __forceinline__ unsigned pack_split(float f) {
  unsigned short hi = f2bf(f);
  float res = f - bf2f(hi);
  unsigned short lo = f2bf(res);
  return (((unsigned)hi) << 16) | (unsigned)lo;
}
// 8 packed elems (2x uint4) -> hi-frag / lo-frag (8 bf16 each)
__device__ __forceinline__ void unpack2(uint4 a0, uint4 a1, bf16x8& hi, bf16x8& lo) {
  union { bf16x8 v; unsigned u[4]; } H, L;
  H.u[0] = (a0.x >> 16) | (a0.y & 0xffff0000u);
  L.u[0] = (a0.x & 0xffffu) | (a0.y << 16);
  H.u[1] = (a0.z >> 16) | (a0.w & 0xffff0000u);
  L.u[1] = (a0.z & 0xffffu) | (a0.w << 16);
  H.u[2] = (a1.x >> 16) | (a1.y & 0xffff0000u);
  L.u[2] = (a1.x & 0xffffu) | (a1.y << 16);
  H.u[3] = (a1.z >> 16) | (a1.w & 0xffff0000u);
  L.u[3] = (a1.z & 0xffffu) | (a1.w << 16);
  hi = H.v; lo = L.v;
}
__device__ __forceinline__ float sigm(float x) { return 1.0f / (1.0f + __expf(-x)); }
__device__ __forceinline__ float tanh_f(float x) { return 1.0f - 2.0f / (__expf(2.0f * x) + 1.0f); }

// ---------- prep: pack weights / W_fc / x_init into split-bf16 uint32 ----------
__global__ __launch_bounds__(256) void prep_kernel(
    const float* __restrict__ wih, const float* __restrict__ whh,
    const float* __restrict__ wfc_in, const float* __restrict__ hin,
    unsigned* __restrict__ wpk, unsigned* __restrict__ wfc, unsigned* __restrict__ xinit) {
  for (int e = 0; e < 8; ++e) {
    unsigned idx = blockIdx.x * 2048u + (unsigned)e * 256u + threadIdx.x;
    if (idx < 16777216u) {                   // wpk [2][4096][2048]
      unsigned l = idx >> 23;
      unsigned r = idx & 8388607u;
      unsigned j = r >> 11;
      unsigned kk = r & 2047u;
      float v = (kk < 1024u) ? wih[(l << 22) + (j << 10) + kk]
                             : whh[(l << 22) + (j << 10) + (kk - 1024u)];
      wpk[idx] = pack_split(v);
    } else if (idx < 17825792u) {            // wfc [1024][1024]
      unsigned i2 = idx - 16777216u;
      wfc[i2] = pack_split(wfc_in[i2]);
    } else if (idx < 17891328u) {            // xinit [64][1024]
      unsigned i3 = idx - 17825792u;
      xinit[i3] = pack_split(hin[i3]);
    }
  }
}

// ---------- grid barrier (plain launch; residency is capacity-guaranteed:
// 256 blocks = #CUs, 64 KB LDS of 160 KB -> >=2 blocks/CU under any placement) ----------
__device__ __forceinline__ void grid_barrier(unsigned* barp, unsigned& mygen) {
  __syncthreads();
  if (threadIdx.x == 0) {
    __threadfence();  // make this block's global writes visible device-wide
    unsigned arr = __hip_atomic_fetch_add(&barp[0], 1u, __ATOMIC_ACQ_REL, __HIP_MEMORY_SCOPE_AGENT);
    if (arr == NBLK - 1u) {
      __hip_atomic_store(&barp[0], 0u, __ATOMIC_RELAXED, __HIP_MEMORY_SCOPE_AGENT);
      __hip_atomic_fetch_add(&barp[1], 1u, __ATOMIC_RELEASE, __HIP_MEMORY_SCOPE_AGENT);
    } else {
      while (__hip_atomic_load(&barp[1], __ATOMIC_ACQUIRE, __HIP_MEMORY_SCOPE_AGENT) == mygen) {
        __builtin_amdgcn_s_sleep(1);
      }
    }
    mygen++;
  }
  __syncthreads();
}

// ---------- main persistent LSTM kernel ----------
// Grid: 256 WGs x 256 thr. WG = (pn, pk): pn in [0,32) owns 128 gate cols, pk in [0,8) owns 256 K cols.
// Per layer-step: GEMM partial -> barrier -> elementwise (c,h update) -> barrier.
__global__ __launch_bounds__(256) void lstm_main(
    const unsigned* __restrict__ wpk, const unsigned* __restrict__ xinit,
    unsigned* __restrict__ h0, unsigned* __restrict__ h1,
    float* __restrict__ c0, float* __restrict__ c1,
    float* __restrict__ part, unsigned* __restrict__ rec,
    const float* __restrict__ bih, const float* __restrict__ bhh,
    unsigned* __restrict__ barp) {
  __shared__ unsigned lds_a[16384];  // 64 rows x 256 packed, XOR-swizzled, 64 KB

  const int tid = threadIdx.x;
  const int wid = blockIdx.x;
  const int pk = wid & 7;
  const int pn = wid >> 3;
  const int wave = tid >> 6;
  const int lane = tid & 63;
  const int q = lane >> 4;      // quad
  const int m16 = lane & 15;
  const int kb = (pk & 3) << 8; // element-col base within the source activation buffer
  const int nbase = (pn << 7) + (wave << 5);  // this wave's 32 gate cols
  const int gtid = (wid << 8) + tid;          // 0..65535
  const int eb = gtid >> 10;                  // batch row for EW
  const int ej = gtid & 1023;                 // h col for EW
  const f32x4 fzero = {0.0f, 0.0f, 0.0f, 0.0f};
  unsigned mygen = 0;

  for (int t = 0; t < 128; ++t) {
    for (int l = 0; l < 2; ++l) {
      // ---- GEMM phase: partial gates for (pn, pk) tile ----
      const unsigned* Xsrc = (l == 0) ? (t == 0 ? xinit : h1) : h0;
      const unsigned* Hsrc = (l == 0) ? h0 : h1;
      const unsigned* Asrc = (pk < 4) ? Xsrc : Hsrc;

      // stage A[64][256] packed into LDS (swizzled: col' = col ^ ((row&3)<<3))
      #pragma unroll
      for (int i = 0; i < 16; ++i) {
        int idx = (i << 8) + tid;          // 0..4095 chunks of 4 dwords
        int r = idx >> 6;
        int cc = (idx & 63) << 2;
        uint4 v = *(const uint4*)(Asrc + (r << 10) + kb + cc);
        *(uint4*)(lds_a + (r << 8) + (cc ^ ((r & 3) << 3))) = v;
      }
      __syncthreads();

      f32x4 acc[4][2];
      for (int mt = 0; mt < 4; ++mt)
        for (int nt = 0; nt < 2; ++nt) acc[mt][nt] = fzero;

      const unsigned* wl = wpk + ((unsigned)l << 23);
      for (int kc = 0; kc < 8; ++kc) {
        bf16x8 ahi[4], alo[4];
        #pragma unroll
        for (int mt = 0; mt < 4; ++mt) {
          int arow = (mt << 4) + m16;       // A m-row = lane&15
          int cs = ((kc << 5) + (q << 3)) ^ ((arow & 3) << 3);
          uint4 a0 = *(const uint4*)(lds_a + (arow << 8) + cs);
          uint4 a1 = *(const uint4*)(lds_a + (arow << 8) + cs + 4);
          unpack2(a0, a1, ahi[mt], alo[mt]);
        }
        #pragma unroll
        for (int nt = 0; nt < 2; ++nt) {
          int wrow = nbase + (nt << 4) + m16;  // B n = lane&15
          const unsigned* wp = wl + ((unsigned)wrow << 11) + (pk << 8) + (kc << 5) + (q << 3);
          uint4 b0 = *(const uint4*)wp;
          uint4 b1 = *(const uint4*)(wp + 4);
          bf16x8 bhi, blo;
          unpack2(b0, b1, bhi, blo);
          #pragma unroll
          for (int mt = 0; mt < 4; ++mt) {
            acc[mt][nt] = __builtin_amdgcn_mfma_f32_16x16x32_bf16(ahi[mt], bhi, acc[mt][nt], 0, 0, 0);
            acc[mt][nt] = __builtin_amdgcn_mfma_f32_16x16x32_bf16(ahi[mt], blo, acc[mt][nt], 0, 0, 0);
            acc[mt][nt] = __builtin_amdgcn_mfma_f32_16x16x32_bf16(alo[mt], bhi, acc[mt][nt], 0, 0, 0);
          }
        }
      }
      // write partial C: part[pk][b][n]  (C/D: col=lane&15, row=q*4+reg)
      float* pb = part + ((unsigned)pk << 18);
      #pragma unroll
      for (int mt = 0; mt < 4; ++mt)
        #pragma unroll
        for (int nt = 0; nt < 2; ++nt) {
          int n = nbase + (nt << 4) + m16;
          #pragma unroll
          for (int r2 = 0; r2 < 4; ++r2) {
            int bb = (mt << 4) + (q << 2) + r2;
            pb[(bb << 12) + n] = acc[mt][nt][r2];
          }
        }
      grid_barrier(barp, mygen);

      // ---- Elementwise phase: one thread per (b, j) ----
      {
        float g4[4];
        #pragma unroll
        for (int gi = 0; gi < 4; ++gi) {
          int col = (gi << 10) + ej;
          float s = bih[(l << 12) + col] + bhh[(l << 12) + col];
          #pragma unroll
          for (int p2 = 0; p2 < 8; ++p2) s += part[(p2 << 18) + (eb << 12) + col];
          g4[gi] = s;
        }
        float* cb = l ? c1 : c0;
        unsigned* hb = l ? h1 : h0;
        float cold = cb[gtid];
        float ig = sigm(g4[0]);
        float fg = sigm(g4[1]);
        float gv = tanh_f(g4[2]);
        float og = sigm(g4[3]);
        float cn = fg * cold + ig * gv;
        float hn = og * tanh_f(cn);
        cb[gtid] = cn;
        unsigned hp = pack_split(hn);
        hb[gtid] = hp;
        if (l == 1) rec[((unsigned)t << 16) + gtid] = hp;
      }
      grid_barrier(barp, mygen);
    }
  }
}

// ---------- FC: out[8192,1024] = rec[8192,1024] @ Wfc^T + b_fc (split-bf16 MFMA) ----------
__global__ __launch_bounds__(256) void fc_kernel(
    const unsigned* __restrict__ rec, const unsigned* __restrict__ wfc,
    const float* __restrict__ bfc, float* __restrict__ out) {
  __shared__ unsigned a_lds[128 * 36];
  __shared__ unsigned w_lds[128 * 36];
  const int tid = threadIdx.x;
  const int wave = tid >> 6;
  const int lane = tid & 63;
  const int q = lane >> 4;
  const int m16 = lane & 15;
  const int m0 = (blockIdx.x >> 3) << 7;   // 64 M-tiles of 128
  const int n0 = (blockIdx.x & 7) << 7;    // 8 N-tiles of 128
  const f32x4 fzero = {0.0f, 0.0f, 0.0f, 0.0f};

  f32x4 acc[2][8];
  for (int mt = 0; mt < 2; ++mt)
    for (int nt = 0; nt < 8; ++nt) acc[mt][nt] = fzero;

  for (int kc = 0; kc < 32; ++kc) {
    __syncthreads();
    #pragma unroll
    for (int i = 0; i < 4; ++i) {
      int c = (i << 8) + tid;     // 0..1023 chunks
      int r = c >> 3;
      int cc = (c & 7) << 2;
      *(uint4*)(a_lds + r * 36 + cc) = *(const uint4*)(rec + ((m0 + r) << 10) + (kc << 5) + cc);
      *(uint4*)(w_lds + r * 36 + cc) = *(const uint4*)(wfc + ((n0 + r) << 10) + (kc << 5) + cc);
    }
    __syncthreads();

    bf16x8 ahi[2], alo[2];
    #pragma unroll
    for (int mt = 0; mt < 2; ++mt) {
      int arow = (wave << 5) + (mt << 4) + m16;
      uint4 a0 = *(const uint4*)(a_lds + arow * 36 + (q << 3));
      uint4 a1 = *(const uint4*)(a_lds + arow * 36 + (q << 3) + 4);
      unpack2(a0, a1, ahi[mt], alo[mt]);
    }
    #pragma unroll
    for (int nt = 0; nt < 8; ++nt) {
      int wrow = (nt << 4) + m16;
      uint4 b0 = *(const uint4*)(w_lds + wrow * 36 + (q << 3));
      uint4 b1 = *(const uint4*)(w_lds + wrow * 36 + (q << 3) + 4);
      bf16x8 bhi, blo;
      unpack2(b0, b1, bhi, blo);
      #pragma unroll
      for (int mt = 0; mt < 2; ++mt) {
        acc[mt][nt] = __builtin_amdgcn_mfma_f32_16x16x32_bf16(ahi[mt], bhi, acc[mt][nt], 0, 0, 0);
        acc[mt][nt] = __builtin_amdgcn_mfma_f32_16x16x32_bf16(ahi[mt], blo, acc[mt][nt], 0, 0, 0);
        acc[mt][nt] = __builtin_amdgcn_mfma_f32_16x16x32_bf16(alo[mt], bhi, acc[mt][nt], 0, 0, 0);
      }
    }
  }
  #pragma unroll
  for (int mt = 0; mt < 2; ++mt)
    #pragma unroll
    for (int nt = 0; nt < 8; ++nt) {
      int n = n0 + (nt << 4) + m16;
      float bv = bfc[n];
      #pragma unroll
      for (int r2 = 0; r2 < 4; ++r2) {
        int m = m0 + (wave << 5) + (mt << 4) + (q << 2) + r2;
        out[(m << 10) + n] = acc[mt][nt][r2] + bv;
      }
    }
}

// ---------- launch ----------
extern "C" void kernel_launch(void* const* d_in, const int* in_sizes, int n_in,
                              void* d_out, int out_size, void* d_ws, size_t ws_size,
                              hipStream_t stream) {
  const float* h_in = (const float*)d_in[0];
  const float* W_ih = (const float*)d_in[1];
  const float* W_hh = (const float*)d_in[2];
  const float* b_ih = (const float*)d_in[3];
  const float* b_hh = (const float*)d_in[4];
  const float* W_fc = (const float*)d_in[5];
  const float* b_fc = (const float*)d_in[6];
  (void)in_sizes; (void)n_in; (void)out_size; (void)ws_size;

  char* ws = (char*)d_ws;
  unsigned* wpk   = (unsigned*)(ws + 0);          // 64 MB: [2][4096][2048] packed
  unsigned* wfc   = (unsigned*)(ws + 67108864);   // 4 MB:  [1024][1024] packed
  unsigned* xinit = (unsigned*)(ws + 71303168);   // 256 KB
  unsigned* h0    = (unsigned*)(ws + 71565312);   // 256 KB
  unsigned* h1    = (unsigned*)(ws + 71827456);   // 256 KB
  float*    c0    = (float*)(ws + 72089600);      // 256 KB
  float*    c1    = (float*)(ws + 72351744);      // 256 KB
  unsigned* barp  = (unsigned*)(ws + 72613888);   // 256 B
  float*    part  = (float*)(ws + 72614144);      // 8 MB: [8][64][4096]
  unsigned* rec   = (unsigned*)(ws + 81002752);   // 32 MB: [128][64][1024] packed
  float*    out   = (float*)d_out;

  // zero h0,h1,c0,c1 + barrier state (contiguous region)
  hipMemsetAsync(ws + 71565312, 0, 4 * 262144 + 256, stream);

  prep_kernel<<<dim3(8736), dim3(256), 0, stream>>>(W_ih, W_hh, W_fc, h_in, wpk, wfc, xinit);

  lstm_main<<<dim3(NBLK), dim3(256), 0, stream>>>(wpk, xinit, h0, h1, c0, c1, part, rec,
                                                  b_ih, b_hh, barp);

  fc_kernel<<<dim3(512), dim3(256), 0, stream>>>(rec, wfc, b_fc, out);
}

// Round 4
// 11632.735 us; speedup vs baseline: 2.0148x; 2.0148x over previous
//
#include <hip/hip_runtime.h>

typedef __attribute__((ext_vector_type(8))) short bf16x8;
typedef __attribute__((ext_vector_type(4))) float f32x4;

#define NBLK 256

// ---------- helpers ----------
__device__ __forceinline__ unsigned short f2bf(float f) {
  unsigned u = __float_as_uint(f);
  unsigned r = u + 0x7fffu + ((u >> 16) & 1u);   // RNE
  return (unsigned short)(r >> 16);
}
__device__ __forceinline__ float bf2f(unsigned short h) {
  return __uint_as_float(((unsigned)h) << 16);
}
// packed = (hi_bits<<16) | lo_bits ; hi+lo reconstructs f to ~2^-16 rel
__device__ __forceinline__ unsigned pack_split(float f) {
  unsigned short hi = f2bf(f);
  float res = f - bf2f(hi);
  unsigned short lo = f2bf(res);
  return (((unsigned)hi) << 16) | (unsigned)lo;
}
// 8 packed elems (2x uint4) -> hi-frag / lo-frag (8 bf16 each)
__device__ __forceinline__ void unpack2(uint4 a0, uint4 a1, bf16x8& hi, bf16x8& lo) {
  union { bf16x8 v; unsigned u[4]; } H, L;
  H.u[0] = (a0.x >> 16) | (a0.y & 0xffff0000u);
  L.u[0] = (a0.x & 0xffffu) | (a0.y << 16);
  H.u[1] = (a0.z >> 16) | (a0.w & 0xffff0000u);
  L.u[1] = (a0.z & 0xffffu) | (a0.w << 16);
  H.u[2] = (a1.x >> 16) | (a1.y & 0xffff0000u);
  L.u[2] = (a1.x & 0xffffu) | (a1.y << 16);
  H.u[3] = (a1.z >> 16) | (a1.w & 0xffff0000u);
  L.u[3] = (a1.z & 0xffffu) | (a1.w << 16);
  hi = H.v; lo = L.v;
}
__device__ __forceinline__ float sigm(float x) { return 1.0f / (1.0f + __expf(-x)); }
__device__ __forceinline__ float tanh_f(float x) { return 1.0f - 2.0f / (__expf(2.0f * x) + 1.0f); }

// ---------- prep: pack weights into per-(WG,wave,layer,ktile) register-load layout ----------
// wreg[wg=256][wave=8][l=2][kt=8][lane=64][e=8] packed dwords.
// For (wg,wave,l,kt,lane,e): n=lane&15, q=lane>>4, g=n>>2, jj=n&3,
//   col = g*1024 + wg*4 + jj,  k = wave*256 + kt*32 + q*8 + e  (k<1024 -> W_ih, else W_hh)
__global__ __launch_bounds__(256) void prep_kernel(
    const float* __restrict__ wih, const float* __restrict__ whh,
    const float* __restrict__ wfc_in, const float* __restrict__ hin,
    unsigned* __restrict__ wreg, unsigned* __restrict__ wfc, unsigned* __restrict__ hb11) {
  for (int e0 = 0; e0 < 8; ++e0) {
    unsigned idx = blockIdx.x * 2048u + (unsigned)e0 * 256u + threadIdx.x;
    if (idx < 16777216u) {
      unsigned wg   = idx >> 16;
      unsigned r    = idx & 65535u;
      unsigned wv   = r >> 13;
      unsigned r2   = r & 8191u;
      unsigned l    = r2 >> 12;
      unsigned r3   = r2 & 4095u;
      unsigned kt   = r3 >> 9;
      unsigned r4   = r3 & 511u;
      unsigned lane = r4 >> 3;
      unsigned e    = r4 & 7u;
      unsigned n = lane & 15u, q = lane >> 4;
      unsigned g = n >> 2, jj = n & 3u;
      unsigned col = (g << 10) + (wg << 2) + jj;
      unsigned k = (wv << 8) + (kt << 5) + (q << 3) + e;
      float v = (k < 1024u) ? wih[(l << 22) + (col << 10) + k]
                            : whh[(l << 22) + (col << 10) + (k - 1024u)];
      wreg[idx] = pack_split(v);
    } else if (idx < 17825792u) {            // wfc [1024][1024]
      unsigned i2 = idx - 16777216u;
      wfc[i2] = pack_split(wfc_in[i2]);
    } else if (idx < 17891328u) {            // x_init packed -> hb[1][1]
      unsigned i3 = idx - 17825792u;
      hb11[i3] = pack_split(hin[i3]);
    }
  }
}

// ---------- grid barrier (residency capacity-guaranteed: 256 blocks = #CUs) ----------
__device__ __forceinline__ void grid_barrier(unsigned* barp, unsigned& mygen) {
  __syncthreads();
  if (threadIdx.x == 0) {
    __threadfence();
    unsigned arr = __hip_atomic_fetch_add(&barp[0], 1u, __ATOMIC_ACQ_REL, __HIP_MEMORY_SCOPE_AGENT);
    if (arr == NBLK - 1u) {
      __hip_atomic_store(&barp[0], 0u, __ATOMIC_RELAXED, __HIP_MEMORY_SCOPE_AGENT);
      __hip_atomic_fetch_add(&barp[1], 1u, __ATOMIC_RELEASE, __HIP_MEMORY_SCOPE_AGENT);
    } else {
      while (__hip_atomic_load(&barp[1], __ATOMIC_ACQUIRE, __HIP_MEMORY_SCOPE_AGENT) == mygen) {
        __builtin_amdgcn_s_sleep(1);
      }
    }
    mygen++;
  }
  __syncthreads();
}

// ---------- main persistent LSTM: weights resident in VGPRs ----------
// 256 WGs x 512 thr (8 waves). WG owns 16 gate-cols {g*1024 + wg*4 + jj}; waves split K=2048.
// Per layer-phase: MFMA over reg-weights -> LDS reduce -> EW (c in regs) -> grid barrier.
__global__ __launch_bounds__(512, 2) void lstm_main(
    const unsigned* __restrict__ wreg, unsigned* hbase,
    const unsigned* __restrict__ hzero,
    unsigned* __restrict__ rec,
    const float* __restrict__ bih, const float* __restrict__ bhh,
    unsigned* __restrict__ barp) {
  __shared__ float lds_p[8 * 1088];  // [wave][m=64][n=16] stride 17 (pad), ~34 KB

  const int tid = threadIdx.x;
  const int wid = blockIdx.x;
  const int wave = tid >> 6;
  const int lane = tid & 63;
  const int q = lane >> 4;
  const int m16 = lane & 15;
  unsigned mygen = 0;

  unsigned* hb[2][2];
  hb[0][0] = hbase;
  hb[0][1] = hbase + 65536;
  hb[1][0] = hbase + 131072;
  hb[1][1] = hbase + 196608;   // holds packed x_init (layer-0 input at t=0)

  // ---- load this wave's weight slice into registers (128 VGPRs) ----
  bf16x8 whi[2][8], wlo[2][8];
  {
    const unsigned* wb = wreg + ((size_t)wid << 16) + ((size_t)wave << 13) + (lane << 3);
    #pragma unroll
    for (int l = 0; l < 2; ++l)
      #pragma unroll
      for (int kt = 0; kt < 8; ++kt) {
        const unsigned* p = wb + (l << 12) + (kt << 9);
        uint4 a0 = *(const uint4*)p;
        uint4 a1 = *(const uint4*)(p + 4);
        unpack2(a0, a1, whi[l][kt], wlo[l][kt]);
      }
  }

  // EW thread state (threads 0..255 own (b=tid>>2, jj=tid&3))
  const int eb = tid >> 2;
  const int ej = tid & 3;
  float creg[2] = {0.0f, 0.0f};
  float biasr[2][4] = {{0, 0, 0, 0}, {0, 0, 0, 0}};
  if (tid < 256) {
    #pragma unroll
    for (int l = 0; l < 2; ++l)
      #pragma unroll
      for (int g = 0; g < 4; ++g) {
        int col = (g << 10) + (wid << 2) + ej;
        biasr[l][g] = bih[(l << 12) + col] + bhh[(l << 12) + col];
      }
  }

  const int colb = (wave & 3) << 8;  // wave's 256-dword K-slice within its source buffer
  const f32x4 fzero = {0.0f, 0.0f, 0.0f, 0.0f};

  for (int t = 0; t < 128; ++t) {
    const int cp = t & 1, pp = cp ^ 1;
    #pragma unroll
    for (int l = 0; l < 2; ++l) {
      const unsigned* xs = (l == 0) ? hb[1][pp] : hb[0][cp];
      // FIX (round-3 bug): layer 1's initial hidden is ZERO, but hb[1][1] was
      // aliased to x_init (layer-0's t=0 input). Use dedicated zero buffer at t=0.
      const unsigned* hs = (l == 0) ? hb[0][pp] : ((t == 0) ? hzero : hb[1][pp]);
      unsigned* dst = (l == 0) ? hb[0][cp] : hb[1][cp];

      // waves 0-3 cover x-part of K (cols 0..1023), waves 4-7 cover h-part
      const unsigned* Ab = ((wave < 4) ? xs : hs) + colb + (q << 3);

      f32x4 acc[4];
      #pragma unroll
      for (int mt = 0; mt < 4; ++mt) acc[mt] = fzero;

      #pragma unroll
      for (int kt = 0; kt < 8; ++kt) {
        #pragma unroll
        for (int mt = 0; mt < 4; ++mt) {
          const unsigned* ap = Ab + (((mt << 4) + m16) << 10) + (kt << 5);
          uint4 a0 = *(const uint4*)ap;
          uint4 a1 = *(const uint4*)(ap + 4);
          bf16x8 ahi, alo;
          unpack2(a0, a1, ahi, alo);
          acc[mt] = __builtin_amdgcn_mfma_f32_16x16x32_bf16(ahi, whi[l][kt], acc[mt], 0, 0, 0);
          acc[mt] = __builtin_amdgcn_mfma_f32_16x16x32_bf16(ahi, wlo[l][kt], acc[mt], 0, 0, 0);
          acc[mt] = __builtin_amdgcn_mfma_f32_16x16x32_bf16(alo, whi[l][kt], acc[mt], 0, 0, 0);
        }
      }

      // partials -> LDS  (C/D: n=lane&15, m-within-tile = q*4+r)
      #pragma unroll
      for (int mt = 0; mt < 4; ++mt)
        #pragma unroll
        for (int r = 0; r < 4; ++r) {
          int m = (mt << 4) + (q << 2) + r;
          lds_p[wave * 1088 + m * 17 + m16] = acc[mt][r];
        }
      __syncthreads();

      // reduce across 8 waves + elementwise (c,h) for this WG's 4 j's x 64 b
      if (tid < 256) {
        float g4[4];
        #pragma unroll
        for (int g = 0; g < 4; ++g) {
          float s = biasr[l][g];
          #pragma unroll
          for (int w = 0; w < 8; ++w) s += lds_p[w * 1088 + eb * 17 + (g << 2) + ej];
          g4[g] = s;
        }
        float ig = sigm(g4[0]);
        float fg = sigm(g4[1]);
        float gv = tanh_f(g4[2]);
        float og = sigm(g4[3]);
        float cn = fg * creg[l] + ig * gv;
        float hn = og * tanh_f(cn);
        creg[l] = cn;
        unsigned hp = pack_split(hn);
        int off = (eb << 10) + (wid << 2) + ej;
        dst[off] = hp;
        if (l == 1) rec[(t << 16) + off] = hp;
      }
      grid_barrier(barp, mygen);
    }
  }
}

// ---------- FC: out[8192,1024] = rec @ Wfc^T + b_fc (split-bf16 MFMA) ----------
__global__ __launch_bounds__(256) void fc_kernel(
    const unsigned* __restrict__ rec, const unsigned* __restrict__ wfc,
    const float* __restrict__ bfc, float* __restrict__ out) {
  __shared__ unsigned a_lds[128 * 36];
  __shared__ unsigned w_lds[128 * 36];
  const int tid = threadIdx.x;
  const int wave = tid >> 6;
  const int lane = tid & 63;
  const int q = lane >> 4;
  const int m16 = lane & 15;
  const int m0 = (blockIdx.x >> 3) << 7;
  const int n0 = (blockIdx.x & 7) << 7;
  const f32x4 fzero = {0.0f, 0.0f, 0.0f, 0.0f};

  f32x4 acc[2][8];
  for (int mt = 0; mt < 2; ++mt)
    for (int nt = 0; nt < 8; ++nt) acc[mt][nt] = fzero;

  for (int kc = 0; kc < 32; ++kc) {
    __syncthreads();
    #pragma unroll
    for (int i = 0; i < 4; ++i) {
      int c = (i << 8) + tid;
      int r = c >> 3;
      int cc = (c & 7) << 2;
      *(uint4*)(a_lds + r * 36 + cc) = *(const uint4*)(rec + ((m0 + r) << 10) + (kc << 5) + cc);
      *(uint4*)(w_lds + r * 36 + cc) = *(const uint4*)(wfc + ((n0 + r) << 10) + (kc << 5) + cc);
    }
    __syncthreads();

    bf16x8 ahi[2], alo[2];
    #pragma unroll
    for (int mt = 0; mt < 2; ++mt) {
      int arow = (wave << 5) + (mt << 4) + m16;
      uint4 a0 = *(const uint4*)(a_lds + arow * 36 + (q << 3));
      uint4 a1 = *(const uint4*)(a_lds + arow * 36 + (q << 3) + 4);
      unpack2(a0, a1, ahi[mt], alo[mt]);
    }
    #pragma unroll
    for (int nt = 0; nt < 8; ++nt) {
      int wrow = (nt << 4) + m16;
      uint4 b0 = *(const uint4*)(w_lds + wrow * 36 + (q << 3));
      uint4 b1 = *(const uint4*)(w_lds + wrow * 36 + (q << 3) + 4);
      bf16x8 bhi, blo;
      unpack2(b0, b1, bhi, blo);
      #pragma unroll
      for (int mt = 0; mt < 2; ++mt) {
        acc[mt][nt] = __builtin_amdgcn_mfma_f32_16x16x32_bf16(ahi[mt], bhi, acc[mt][nt], 0, 0, 0);
        acc[mt][nt] = __builtin_amdgcn_mfma_f32_16x16x32_bf16(ahi[mt], blo, acc[mt][nt], 0, 0, 0);
        acc[mt][nt] = __builtin_amdgcn_mfma_f32_16x16x32_bf16(alo[mt], bhi, acc[mt][nt], 0, 0, 0);
      }
    }
  }
  #pragma unroll
  for (int mt = 0; mt < 2; ++mt)
    #pragma unroll
    for (int nt = 0; nt < 8; ++nt) {
      int n = n0 + (nt << 4) + m16;
      float bv = bfc[n];
      #pragma unroll
      for (int r2 = 0; r2 < 4; ++r2) {
        int m = m0 + (wave << 5) + (mt << 4) + (q << 2) + r2;
        out[(m << 10) + n] = acc[mt][nt][r2] + bv;
      }
    }
}

// ---------- launch ----------
extern "C" void kernel_launch(void* const* d_in, const int* in_sizes, int n_in,
                              void* d_out, int out_size, void* d_ws, size_t ws_size,
                              hipStream_t stream) {
  const float* h_in = (const float*)d_in[0];
  const float* W_ih = (const float*)d_in[1];
  const float* W_hh = (const float*)d_in[2];
  const float* b_ih = (const float*)d_in[3];
  const float* b_hh = (const float*)d_in[4];
  const float* W_fc = (const float*)d_in[5];
  const float* b_fc = (const float*)d_in[6];
  (void)in_sizes; (void)n_in; (void)out_size; (void)ws_size;

  char* ws = (char*)d_ws;
  unsigned* wreg  = (unsigned*)(ws + 0);          // 64 MB: [256][8][2][8][64][8]
  unsigned* wfc   = (unsigned*)(ws + 67108864);   // 4 MB
  unsigned* hbase = (unsigned*)(ws + 71303168);   // 1 MB: hb[2][2] of 256 KB
  unsigned* hzero = (unsigned*)(ws + 72351744);   // 256 KB, stays zero (layer-1 init hidden)
  unsigned* barp  = (unsigned*)(ws + 72613888);   // 256 B
  unsigned* rec   = (unsigned*)(ws + 72614144);   // 32 MB: [128][64][1024] packed
  float*    out   = (float*)d_out;

  // zero: hb[0][1] (layer-0 init hidden), hzero + barp (contiguous)
  hipMemsetAsync(ws + 71303168 + 262144, 0, 262144, stream);
  hipMemsetAsync(ws + 72351744, 0, 262144 + 256, stream);

  prep_kernel<<<dim3(8736), dim3(256), 0, stream>>>(W_ih, W_hh, W_fc, h_in,
                                                    wreg, wfc, hbase + 196608);

  lstm_main<<<dim3(NBLK), dim3(512), 0, stream>>>(wreg, hbase, hzero, rec, b_ih, b_hh, barp);

  fc_kernel<<<dim3(512), dim3(256), 0, stream>>>(rec, wfc, b_fc, out);
}

// Round 6
// 6762.330 us; speedup vs baseline: 3.4660x; 1.7202x over previous
//
#include <hip/hip_runtime.h>

typedef __attribute__((ext_vector_type(8))) short bf16x8;
typedef __attribute__((ext_vector_type(4))) float f32x4;

#define NBLK 256

// ---------- helpers ----------
__device__ __forceinline__ unsigned short f2bf(float f) {
  unsigned u = __float_as_uint(f);
  unsigned r = u + 0x7fffu + ((u >> 16) & 1u);   // RNE
  return (unsigned short)(r >> 16);
}
__device__ __forceinline__ float bf2f(unsigned short h) {
  return __uint_as_float(((unsigned)h) << 16);
}
// packed = (hi_bits<<16) | lo_bits ; hi+lo reconstructs f to ~2^-16 rel
__device__ __forceinline__ unsigned pack_split(float f) {
  unsigned short hi = f2bf(f);
  float res = f - bf2f(hi);
  unsigned short lo = f2bf(res);
  return (((unsigned)hi) << 16) | (unsigned)lo;
}
// 8 packed elems (2x uint4) -> hi-frag / lo-frag (8 bf16 each)
__device__ __forceinline__ void unpack2(uint4 a0, uint4 a1, bf16x8& hi, bf16x8& lo) {
  union { bf16x8 v; unsigned u[4]; } H, L;
  H.u[0] = (a0.x >> 16) | (a0.y & 0xffff0000u);
  L.u[0] = (a0.x & 0xffffu) | (a0.y << 16);
  H.u[1] = (a0.z >> 16) | (a0.w & 0xffff0000u);
  L.u[1] = (a0.z & 0xffffu) | (a0.w << 16);
  H.u[2] = (a1.x >> 16) | (a1.y & 0xffff0000u);
  L.u[2] = (a1.x & 0xffffu) | (a1.y << 16);
  H.u[3] = (a1.z >> 16) | (a1.w & 0xffff0000u);
  L.u[3] = (a1.z & 0xffffu) | (a1.w << 16);
  hi = H.v; lo = L.v;
}
__device__ __forceinline__ float sigm(float x) { return 1.0f / (1.0f + __expf(-x)); }
__device__ __forceinline__ float tanh_f(float x) { return 1.0f - 2.0f / (__expf(2.0f * x) + 1.0f); }

// ---------- prep: pack weights into per-(WG,wave,layer,ktile) register-load layout ----------
// wreg[wg=256][wave=8][l=2][kt=8][lane=64][e=8] packed dwords.
// For (wg,wave,l,kt,lane,e): n=lane&15, q=lane>>4, g=n>>2, jj=n&3,
//   col = g*1024 + wg*4 + jj,  k = wave*256 + kt*32 + q*8 + e  (k<1024 -> W_ih, else W_hh)
__global__ __launch_bounds__(256) void prep_kernel(
    const float* __restrict__ wih, const float* __restrict__ whh,
    const float* __restrict__ wfc_in, const float* __restrict__ hin,
    unsigned* __restrict__ wreg, unsigned* __restrict__ wfc, unsigned* __restrict__ hb11) {
  for (int e0 = 0; e0 < 8; ++e0) {
    unsigned idx = blockIdx.x * 2048u + (unsigned)e0 * 256u + threadIdx.x;
    if (idx < 16777216u) {
      unsigned wg   = idx >> 16;
      unsigned r    = idx & 65535u;
      unsigned wv   = r >> 13;
      unsigned r2   = r & 8191u;
      unsigned l    = r2 >> 12;
      unsigned r3   = r2 & 4095u;
      unsigned kt   = r3 >> 9;
      unsigned r4   = r3 & 511u;
      unsigned lane = r4 >> 3;
      unsigned e    = r4 & 7u;
      unsigned n = lane & 15u, q = lane >> 4;
      unsigned g = n >> 2, jj = n & 3u;
      unsigned col = (g << 10) + (wg << 2) + jj;
      unsigned k = (wv << 8) + (kt << 5) + (q << 3) + e;
      float v = (k < 1024u) ? wih[(l << 22) + (col << 10) + k]
                            : whh[(l << 22) + (col << 10) + (k - 1024u)];
      wreg[idx] = pack_split(v);
    } else if (idx < 17825792u) {            // wfc [1024][1024]
      unsigned i2 = idx - 16777216u;
      wfc[i2] = pack_split(wfc_in[i2]);
    } else if (idx < 17891328u) {            // x_init packed -> hb[1][1]
      unsigned i3 = idx - 17825792u;
      hb11[i3] = pack_split(hin[i3]);
    }
  }
}

// ---------- distributed grid barrier ----------
// barp[0] = generation word; barp[64 + wid] = per-block arrival flag (distinct words,
// no RMW contention). Block 0 aggregates with 256 parallel relaxed polls, then
// acquire-fence + release-store of generation. Spinners use RELAXED polls (no
// buffer_inv storm) and exactly one acquire fence on exit.
__device__ __forceinline__ void grid_barrier(unsigned* barp, unsigned g,
                                             int wid, int tid) {
  __syncthreads();   // all h/rec stores of this block done (compiler drains vmcnt)
  if (wid == 0) {
    if (tid > 0 && tid < NBLK) {
      while (__hip_atomic_load(&barp[64 + tid], __ATOMIC_RELAXED,
                               __HIP_MEMORY_SCOPE_AGENT) < g) {
        __builtin_amdgcn_s_sleep(1);
      }
    }
    __syncthreads();
    if (tid == 0) {
      __builtin_amdgcn_fence(__ATOMIC_ACQUIRE, "agent");
      __hip_atomic_store(&barp[0], g, __ATOMIC_RELEASE, __HIP_MEMORY_SCOPE_AGENT);
    }
  } else {
    if (tid == 0) {
      __hip_atomic_store(&barp[64 + wid], g, __ATOMIC_RELEASE, __HIP_MEMORY_SCOPE_AGENT);
      while (__hip_atomic_load(&barp[0], __ATOMIC_RELAXED,
                               __HIP_MEMORY_SCOPE_AGENT) < g) {
        __builtin_amdgcn_s_sleep(2);
      }
      __builtin_amdgcn_fence(__ATOMIC_ACQUIRE, "agent");
    }
  }
  __syncthreads();
}

// ---------- main persistent LSTM: weights resident in VGPRs ----------
// 256 WGs x 512 thr (8 waves). WG owns 16 gate-cols {g*1024 + wg*4 + jj}; waves split K=2048.
// Per layer-phase: MFMA over reg-weights -> LDS reduce -> EW (c in regs) -> grid barrier.
__global__ __launch_bounds__(512, 2) void lstm_main(
    const unsigned* __restrict__ wreg, unsigned* hbase,
    const unsigned* __restrict__ hzero,
    unsigned* __restrict__ rec,
    const float* __restrict__ bih, const float* __restrict__ bhh,
    unsigned* __restrict__ barp) {
  __shared__ float lds_p[8 * 1088];  // [wave][m=64][n=16] stride 17 (pad), ~34 KB

  const int tid = threadIdx.x;
  const int wid = blockIdx.x;
  const int wave = tid >> 6;
  const int lane = tid & 63;
  const int q = lane >> 4;
  const int m16 = lane & 15;

  unsigned* hb[2][2];
  hb[0][0] = hbase;
  hb[0][1] = hbase + 65536;
  hb[1][0] = hbase + 131072;
  hb[1][1] = hbase + 196608;   // holds packed x_init (layer-0 input at t=0)

  // ---- load this wave's weight slice into registers (128 VGPRs), then PIN them
  // (empty inline asm defeats the compiler's load-sinking/remat — round-4 counters
  // showed VGPR_Count=120 < 128, i.e. weights were re-loaded every phase) ----
  bf16x8 whi[2][8], wlo[2][8];
  {
    const unsigned* wb = wreg + ((size_t)wid << 16) + ((size_t)wave << 13) + (lane << 3);
    #pragma unroll
    for (int l = 0; l < 2; ++l)
      #pragma unroll
      for (int kt = 0; kt < 8; ++kt) {
        const unsigned* p = wb + (l << 12) + (kt << 9);
        uint4 a0 = *(const uint4*)p;
        uint4 a1 = *(const uint4*)(p + 4);
        unpack2(a0, a1, whi[l][kt], wlo[l][kt]);
      }
    #pragma unroll
    for (int l = 0; l < 2; ++l)
      #pragma unroll
      for (int kt = 0; kt < 8; ++kt) {
        asm volatile("" : "+v"(whi[l][kt]), "+v"(wlo[l][kt]));
      }
  }

  // EW thread state (threads 0..255 own (b=tid>>2, jj=tid&3))
  const int eb = tid >> 2;
  const int ej = tid & 3;
  float creg[2] = {0.0f, 0.0f};
  float biasr[2][4] = {{0, 0, 0, 0}, {0, 0, 0, 0}};
  if (tid < 256) {
    #pragma unroll
    for (int l = 0; l < 2; ++l)
      #pragma unroll
      for (int g = 0; g < 4; ++g) {
        int col = (g << 10) + (wid << 2) + ej;
        biasr[l][g] = bih[(l << 12) + col] + bhh[(l << 12) + col];
      }
  }

  const int colb = (wave & 3) << 8;  // wave's 256-dword K-slice within its source buffer
  const f32x4 fzero = {0.0f, 0.0f, 0.0f, 0.0f};

  for (int t = 0; t < 128; ++t) {
    const int cp = t & 1, pp = cp ^ 1;
    #pragma unroll
    for (int l = 0; l < 2; ++l) {
      const unsigned* xs = (l == 0) ? hb[1][pp] : hb[0][cp];
      // layer 1's initial hidden is ZERO (hb[1][1] aliases x_init) -> dedicated buffer
      const unsigned* hs = (l == 0) ? hb[0][pp] : ((t == 0) ? hzero : hb[1][pp]);
      unsigned* dst = (l == 0) ? hb[0][cp] : hb[1][cp];

      // waves 0-3 cover x-part of K (cols 0..1023), waves 4-7 cover h-part
      const unsigned* Ab = ((wave < 4) ? xs : hs) + colb + (q << 3);

      f32x4 acc[4];
      #pragma unroll
      for (int mt = 0; mt < 4; ++mt) acc[mt] = fzero;

      #pragma unroll
      for (int kt = 0; kt < 8; ++kt) {
        #pragma unroll
        for (int mt = 0; mt < 4; ++mt) {
          const unsigned* ap = Ab + (((mt << 4) + m16) << 10) + (kt << 5);
          uint4 a0 = *(const uint4*)ap;
          uint4 a1 = *(const uint4*)(ap + 4);
          bf16x8 ahi, alo;
          unpack2(a0, a1, ahi, alo);
          acc[mt] = __builtin_amdgcn_mfma_f32_16x16x32_bf16(ahi, whi[l][kt], acc[mt], 0, 0, 0);
          acc[mt] = __builtin_amdgcn_mfma_f32_16x16x32_bf16(ahi, wlo[l][kt], acc[mt], 0, 0, 0);
          acc[mt] = __builtin_amdgcn_mfma_f32_16x16x32_bf16(alo, whi[l][kt], acc[mt], 0, 0, 0);
        }
      }

      // partials -> LDS  (C/D: n=lane&15, m-within-tile = q*4+r)
      #pragma unroll
      for (int mt = 0; mt < 4; ++mt)
        #pragma unroll
        for (int r = 0; r < 4; ++r) {
          int m = (mt << 4) + (q << 2) + r;
          lds_p[wave * 1088 + m * 17 + m16] = acc[mt][r];
        }
      __syncthreads();

      // reduce across 8 waves + elementwise (c,h) for this WG's 4 j's x 64 b
      if (tid < 256) {
        float g4[4];
        #pragma unroll
        for (int g = 0; g < 4; ++g) {
          float s = biasr[l][g];
          #pragma unroll
          for (int w = 0; w < 8; ++w) s += lds_p[w * 1088 + eb * 17 + (g << 2) + ej];
          g4[g] = s;
        }
        float ig = sigm(g4[0]);
        float fg = sigm(g4[1]);
        float gv = tanh_f(g4[2]);
        float og = sigm(g4[3]);
        float cn = fg * creg[l] + ig * gv;
        float hn = og * tanh_f(cn);
        creg[l] = cn;
        unsigned hp = pack_split(hn);
        int off = (eb << 10) + (wid << 2) + ej;
        dst[off] = hp;
        if (l == 1) rec[(t << 16) + off] = hp;
      }
      grid_barrier(barp, (unsigned)(2 * t + l + 1), wid, tid);
    }
  }
}

// ---------- FC: out[8192,1024] = rec @ Wfc^T + b_fc (split-bf16 MFMA) ----------
__global__ __launch_bounds__(256) void fc_kernel(
    const unsigned* __restrict__ rec, const unsigned* __restrict__ wfc,
    const float* __restrict__ bfc, float* __restrict__ out) {
  __shared__ unsigned a_lds[128 * 36];
  __shared__ unsigned w_lds[128 * 36];
  const int tid = threadIdx.x;
  const int wave = tid >> 6;
  const int lane = tid & 63;
  const int q = lane >> 4;
  const int m16 = lane & 15;
  const int m0 = (blockIdx.x >> 3) << 7;
  const int n0 = (blockIdx.x & 7) << 7;
  const f32x4 fzero = {0.0f, 0.0f, 0.0f, 0.0f};

  f32x4 acc[2][8];
  for (int mt = 0; mt < 2; ++mt)
    for (int nt = 0; nt < 8; ++nt) acc[mt][nt] = fzero;

  for (int kc = 0; kc < 32; ++kc) {
    __syncthreads();
    #pragma unroll
    for (int i = 0; i < 4; ++i) {
      int c = (i << 8) + tid;
      int r = c >> 3;
      int cc = (c & 7) << 2;
      *(uint4*)(a_lds + r * 36 + cc) = *(const uint4*)(rec + ((m0 + r) << 10) + (kc << 5) + cc);
      *(uint4*)(w_lds + r * 36 + cc) = *(const uint4*)(wfc + ((n0 + r) << 10) + (kc << 5) + cc);
    }
    __syncthreads();

    bf16x8 ahi[2], alo[2];
    #pragma unroll
    for (int mt = 0; mt < 2; ++mt) {
      int arow = (wave << 5) + (mt << 4) + m16;
      uint4 a0 = *(const uint4*)(a_lds + arow * 36 + (q << 3));
      uint4 a1 = *(const uint4*)(a_lds + arow * 36 + (q << 3) + 4);
      unpack2(a0, a1, ahi[mt], alo[mt]);
    }
    #pragma unroll
    for (int nt = 0; nt < 8; ++nt) {
      int wrow = (nt << 4) + m16;
      uint4 b0 = *(const uint4*)(w_lds + wrow * 36 + (q << 3));
      uint4 b1 = *(const uint4*)(w_lds + wrow * 36 + (q << 3) + 4);
      bf16x8 bhi, blo;
      unpack2(b0, b1, bhi, blo);
      #pragma unroll
      for (int mt = 0; mt < 2; ++mt) {
        acc[mt][nt] = __builtin_amdgcn_mfma_f32_16x16x32_bf16(ahi[mt], bhi, acc[mt][nt], 0, 0, 0);
        acc[mt][nt] = __builtin_amdgcn_mfma_f32_16x16x32_bf16(ahi[mt], blo, acc[mt][nt], 0, 0, 0);
        acc[mt][nt] = __builtin_amdgcn_mfma_f32_16x16x32_bf16(alo[mt], bhi, acc[mt][nt], 0, 0, 0);
      }
    }
  }
  #pragma unroll
  for (int mt = 0; mt < 2; ++mt)
    #pragma unroll
    for (int nt = 0; nt < 8; ++nt) {
      int n = n0 + (nt << 4) + m16;
      float bv = bfc[n];
      #pragma unroll
      for (int r2 = 0; r2 < 4; ++r2) {
        int m = m0 + (wave << 5) + (mt << 4) + (q << 2) + r2;
        out[(m << 10) + n] = acc[mt][nt][r2] + bv;
      }
    }
}

// ---------- launch ----------
extern "C" void kernel_launch(void* const* d_in, const int* in_sizes, int n_in,
                              void* d_out, int out_size, void* d_ws, size_t ws_size,
                              hipStream_t stream) {
  const float* h_in = (const float*)d_in[0];
  const float* W_ih = (const float*)d_in[1];
  const float* W_hh = (const float*)d_in[2];
  const float* b_ih = (const float*)d_in[3];
  const float* b_hh = (const float*)d_in[4];
  const float* W_fc = (const float*)d_in[5];
  const float* b_fc = (const float*)d_in[6];
  (void)in_sizes; (void)n_in; (void)out_size; (void)ws_size;

  char* ws = (char*)d_ws;
  unsigned* wreg  = (unsigned*)(ws + 0);          // 64 MB: [256][8][2][8][64][8]
  unsigned* wfc   = (unsigned*)(ws + 67108864);   // 4 MB
  unsigned* hbase = (unsigned*)(ws + 71303168);   // 1 MB: hb[2][2] of 256 KB
  unsigned* hzero = (unsigned*)(ws + 72351744);   // 256 KB, stays zero (layer-1 init hidden)
  unsigned* barp  = (unsigned*)(ws + 72613888);   // 2 KB: [0]=gen, [64+wid]=arrival flags
  unsigned* rec   = (unsigned*)(ws + 72616192);   // 32 MB: [128][64][1024] packed
  float*    out   = (float*)d_out;

  // zero: hb[0][1] (layer-0 init hidden), hzero + barp (contiguous)
  (void)hipMemsetAsync(ws + 71303168 + 262144, 0, 262144, stream);
  (void)hipMemsetAsync(ws + 72351744, 0, 262144 + 2304, stream);

  prep_kernel<<<dim3(8736), dim3(256), 0, stream>>>(W_ih, W_hh, W_fc, h_in,
                                                    wreg, wfc, hbase + 196608);

  lstm_main<<<dim3(NBLK), dim3(512), 0, stream>>>(wreg, hbase, hzero, rec, b_ih, b_hh, barp);

  fc_kernel<<<dim3(512), dim3(256), 0, stream>>>(rec, wfc, b_fc, out);
}

// Round 7
// 4742.365 us; speedup vs baseline: 4.9422x; 1.4259x over previous
//
#include <hip/hip_runtime.h>

typedef __attribute__((ext_vector_type(8))) short bf16x8;
typedef __attribute__((ext_vector_type(4))) float f32x4;

#define NBLK 256

typedef __attribute__((address_space(3))) unsigned lds_u;
typedef __attribute__((address_space(1))) const unsigned glb_u;

// ---------- helpers ----------
__device__ __forceinline__ unsigned short f2bf(float f) {
  unsigned u = __float_as_uint(f);
  unsigned r = u + 0x7fffu + ((u >> 16) & 1u);   // RNE
  return (unsigned short)(r >> 16);
}
__device__ __forceinline__ float bf2f(unsigned short h) {
  return __uint_as_float(((unsigned)h) << 16);
}
// packed = (hi_bits<<16) | lo_bits ; hi+lo reconstructs f to ~2^-16 rel
__device__ __forceinline__ unsigned pack_split(float f) {
  unsigned short hi = f2bf(f);
  float res = f - bf2f(hi);
  unsigned short lo = f2bf(res);
  return (((unsigned)hi) << 16) | (unsigned)lo;
}
// 8 packed elems (2x uint4) -> hi-frag / lo-frag (8 bf16 each)
__device__ __forceinline__ void unpack2(uint4 a0, uint4 a1, bf16x8& hi, bf16x8& lo) {
  union { bf16x8 v; unsigned u[4]; } H, L;
  H.u[0] = (a0.x >> 16) | (a0.y & 0xffff0000u);
  L.u[0] = (a0.x & 0xffffu) | (a0.y << 16);
  H.u[1] = (a0.z >> 16) | (a0.w & 0xffff0000u);
  L.u[1] = (a0.z & 0xffffu) | (a0.w << 16);
  H.u[2] = (a1.x >> 16) | (a1.y & 0xffff0000u);
  L.u[2] = (a1.x & 0xffffu) | (a1.y << 16);
  H.u[3] = (a1.z >> 16) | (a1.w & 0xffff0000u);
  L.u[3] = (a1.z & 0xffffu) | (a1.w << 16);
  hi = H.v; lo = L.v;
}
__device__ __forceinline__ float sigm(float x) { return 1.0f / (1.0f + __expf(-x)); }
__device__ __forceinline__ float tanh_f(float x) { return 1.0f - 2.0f / (__expf(2.0f * x) + 1.0f); }

// ---------- prep: pack weights into per-(WG,wave,layer,ktile) register-load layout ----------
// wreg[wg=256][wave=8][l=2][kt=8][lane=64][e=8] packed dwords.
// For (wg,wave,l,kt,lane,e): n=lane&15, q=lane>>4, g=n>>2, jj=n&3,
//   col = g*1024 + wg*4 + jj,  k = wave*256 + kt*32 + q*8 + e  (k<1024 -> W_ih, else W_hh)
__global__ __launch_bounds__(256) void prep_kernel(
    const float* __restrict__ wih, const float* __restrict__ whh,
    const float* __restrict__ wfc_in, const float* __restrict__ hin,
    unsigned* __restrict__ wreg, unsigned* __restrict__ wfc, unsigned* __restrict__ hb11) {
  for (int e0 = 0; e0 < 8; ++e0) {
    unsigned idx = blockIdx.x * 2048u + (unsigned)e0 * 256u + threadIdx.x;
    if (idx < 16777216u) {
      unsigned wg   = idx >> 16;
      unsigned r    = idx & 65535u;
      unsigned wv   = r >> 13;
      unsigned r2   = r & 8191u;
      unsigned l    = r2 >> 12;
      unsigned r3   = r2 & 4095u;
      unsigned kt   = r3 >> 9;
      unsigned r4   = r3 & 511u;
      unsigned lane = r4 >> 3;
      unsigned e    = r4 & 7u;
      unsigned n = lane & 15u, q = lane >> 4;
      unsigned g = n >> 2, jj = n & 3u;
      unsigned col = (g << 10) + (wg << 2) + jj;
      unsigned k = (wv << 8) + (kt << 5) + (q << 3) + e;
      float v = (k < 1024u) ? wih[(l << 22) + (col << 10) + k]
                            : whh[(l << 22) + (col << 10) + (k - 1024u)];
      wreg[idx] = pack_split(v);
    } else if (idx < 17825792u) {            // wfc [1024][1024]
      unsigned i2 = idx - 16777216u;
      wfc[i2] = pack_split(wfc_in[i2]);
    } else if (idx < 17891328u) {            // x_init packed -> hb[1][1]
      unsigned i3 = idx - 17825792u;
      hb11[i3] = pack_split(hin[i3]);
    }
  }
}

// ---------- distributed grid barrier (round-6 verified) ----------
__device__ __forceinline__ void grid_barrier(unsigned* barp, unsigned g,
                                             int wid, int tid) {
  __syncthreads();   // drains this block's stores (compiler emits vmcnt(0) before s_barrier)
  if (wid == 0) {
    if (tid > 0 && tid < NBLK) {
      while (__hip_atomic_load(&barp[64 + tid], __ATOMIC_RELAXED,
                               __HIP_MEMORY_SCOPE_AGENT) < g) {
        __builtin_amdgcn_s_sleep(1);
      }
    }
    __syncthreads();
    if (tid == 0) {
      __builtin_amdgcn_fence(__ATOMIC_ACQUIRE, "agent");
      __hip_atomic_store(&barp[0], g, __ATOMIC_RELEASE, __HIP_MEMORY_SCOPE_AGENT);
    }
  } else {
    if (tid == 0) {
      __hip_atomic_store(&barp[64 + wid], g, __ATOMIC_RELEASE, __HIP_MEMORY_SCOPE_AGENT);
      while (__hip_atomic_load(&barp[0], __ATOMIC_RELAXED,
                               __HIP_MEMORY_SCOPE_AGENT) < g) {
        __builtin_amdgcn_s_sleep(2);
      }
      __builtin_amdgcn_fence(__ATOMIC_ACQUIRE, "agent");
    }
  }
  __syncthreads();
}

// ---------- main persistent LSTM: weights in regs, A staged via async global_load_lds ----------
// 256 WGs x 512 thr (8 waves). WG owns 16 gate-cols; waves split K=2048 (each 256 cols).
// Per wave: 8 chunks of A (64 rows x 32 dwords = 8 KB), double-buffered in its own
// 16 KB LDS region. Global-side XOR swizzle (granule slot = c ^ (row&7)) gives
// conflict-free ds_read_b128 fragments despite the forced lane*16 LDS order.
__global__ __launch_bounds__(512, 1) void lstm_main(
    const unsigned* __restrict__ wreg, unsigned* hbase,
    const unsigned* __restrict__ hzero,
    unsigned* __restrict__ rec,
    const float* __restrict__ bih, const float* __restrict__ bhh,
    unsigned* __restrict__ barp) {
  __shared__ unsigned lds_stage[8 * 4096];  // 128 KB: per wave 16 KB (2 bufs x 8 KB)

  const int tid = threadIdx.x;
  const int wid = blockIdx.x;
  const int wave = tid >> 6;
  const int lane = tid & 63;
  const int q = lane >> 4;
  const int m16 = lane & 15;

  unsigned* hb[2][2];
  hb[0][0] = hbase;
  hb[0][1] = hbase + 65536;
  hb[1][0] = hbase + 131072;
  hb[1][1] = hbase + 196608;   // holds packed x_init (layer-0 input at t=0)

  // ---- load this wave's weight slice into registers, then pin ----
  bf16x8 whi[2][8], wlo[2][8];
  {
    const unsigned* wb = wreg + ((size_t)wid << 16) + ((size_t)wave << 13) + (lane << 3);
    #pragma unroll
    for (int l = 0; l < 2; ++l)
      #pragma unroll
      for (int kt = 0; kt < 8; ++kt) {
        const unsigned* p = wb + (l << 12) + (kt << 9);
        uint4 a0 = *(const uint4*)p;
        uint4 a1 = *(const uint4*)(p + 4);
        unpack2(a0, a1, whi[l][kt], wlo[l][kt]);
      }
    #pragma unroll
    for (int l = 0; l < 2; ++l)
      #pragma unroll
      for (int kt = 0; kt < 8; ++kt) {
        asm volatile("" : "+v"(whi[l][kt]), "+v"(wlo[l][kt]));
      }
  }

  // EW thread state (threads 0..255 own (b=tid>>2, jj=tid&3))
  const int eb = tid >> 2;
  const int ej = tid & 3;
  float creg[2] = {0.0f, 0.0f};
  float biasr[2][4] = {{0, 0, 0, 0}, {0, 0, 0, 0}};
  if (tid < 256) {
    #pragma unroll
    for (int l = 0; l < 2; ++l)
      #pragma unroll
      for (int g = 0; g < 4; ++g) {
        int col = (g << 10) + (wid << 2) + ej;
        biasr[l][g] = bih[(l << 12) + col] + bhh[(l << 12) + col];
      }
  }

  const int colb = (wave & 3) << 8;           // wave's 256-dword K-slice
  unsigned* const lds_w = lds_stage + (wave << 12);   // this wave's 16 KB region
  const f32x4 fzero = {0.0f, 0.0f, 0.0f, 0.0f};

  // staging-issue precomputed lane geometry: instr i covers slots s=i*64+lane
  // r = s>>3 (row), cs = s&7 (LDS slot), c = cs ^ (r&7) (global granule)
  const int st_r  = lane >> 3;        // + i*8 per instr
  const int st_cs = lane & 7;

  for (int t = 0; t < 128; ++t) {
    const int cp = t & 1, pp = cp ^ 1;
    #pragma unroll
    for (int l = 0; l < 2; ++l) {
      const unsigned* xs = (l == 0) ? hb[1][pp] : hb[0][cp];
      const unsigned* hs = (l == 0) ? hb[0][pp] : ((t == 0) ? hzero : hb[1][pp]);
      unsigned* dst = (l == 0) ? hb[0][cp] : hb[1][cp];

      const unsigned* src = ((wave < 4) ? xs : hs) + colb;

      // issue chunk kt into buffer bsel (8 x global_load_lds width-16)
      #define ISSUE_CHUNK(kt_, bsel_)                                              \
        {                                                                          \
          _Pragma("unroll")                                                        \
          for (int i = 0; i < 8; ++i) {                                            \
            int r = (i << 3) + st_r;                                               \
            int c = st_cs ^ (r & 7);                                               \
            const unsigned* gp = src + (r << 10) + ((kt_) << 5) + (c << 2);        \
            unsigned* lp = lds_w + ((bsel_) << 11) + (i << 8);                     \
            __builtin_amdgcn_global_load_lds((glb_u*)gp, (lds_u*)lp, 16, 0, 0);    \
          }                                                                        \
        }

      f32x4 acc[4];
      #pragma unroll
      for (int mt = 0; mt < 4; ++mt) acc[mt] = fzero;

      ISSUE_CHUNK(0, 0)
      ISSUE_CHUNK(1, 1)

      #pragma unroll
      for (int kt = 0; kt < 8; ++kt) {
        const int bsel = kt & 1;
        if (kt < 7) {
          asm volatile("s_waitcnt vmcnt(8)" ::: "memory");
        } else {
          asm volatile("s_waitcnt vmcnt(0)" ::: "memory");
        }
        const unsigned* bufb = lds_w + (bsel << 11);
        bf16x8 ahi[4], alo[4];
        #pragma unroll
        for (int mt = 0; mt < 4; ++mt) {
          int row = (mt << 4) + m16;
          const unsigned* base = bufb + (row << 5);
          uint4 a0 = *(const uint4*)(base + ((((q << 1)    ) ^ (row & 7)) << 2));
          uint4 a1 = *(const uint4*)(base + ((((q << 1) | 1) ^ (row & 7)) << 2));
          unpack2(a0, a1, ahi[mt], alo[mt]);
        }
        // frags now in VGPRs; drain LDS pipe before overwriting this buffer
        asm volatile("s_waitcnt lgkmcnt(0)" ::: "memory");
        if (kt < 6) ISSUE_CHUNK(kt + 2, bsel)
        #pragma unroll
        for (int mt = 0; mt < 4; ++mt) {
          acc[mt] = __builtin_amdgcn_mfma_f32_16x16x32_bf16(ahi[mt], whi[l][kt], acc[mt], 0, 0, 0);
          acc[mt] = __builtin_amdgcn_mfma_f32_16x16x32_bf16(ahi[mt], wlo[l][kt], acc[mt], 0, 0, 0);
          acc[mt] = __builtin_amdgcn_mfma_f32_16x16x32_bf16(alo[mt], whi[l][kt], acc[mt], 0, 0, 0);
        }
      }
      #undef ISSUE_CHUNK

      // partials -> this wave's own buf0 region (4352 B < 8 KB; chunks all consumed)
      {
        float* lds_pw = (float*)lds_w;
        #pragma unroll
        for (int mt = 0; mt < 4; ++mt)
          #pragma unroll
          for (int r = 0; r < 4; ++r) {
            int m = (mt << 4) + (q << 2) + r;
            lds_pw[m * 17 + m16] = acc[mt][r];
          }
      }
      __syncthreads();

      // reduce across 8 waves + elementwise (c,h) for this WG's 4 j's x 64 b
      if (tid < 256) {
        float g4[4];
        #pragma unroll
        for (int g = 0; g < 4; ++g) {
          float s = biasr[l][g];
          #pragma unroll
          for (int w = 0; w < 8; ++w)
            s += ((const float*)(lds_stage + (w << 12)))[eb * 17 + (g << 2) + ej];
          g4[g] = s;
        }
        float ig = sigm(g4[0]);
        float fg = sigm(g4[1]);
        float gv = tanh_f(g4[2]);
        float og = sigm(g4[3]);
        float cn = fg * creg[l] + ig * gv;
        float hn = og * tanh_f(cn);
        creg[l] = cn;
        unsigned hp = pack_split(hn);
        int off = (eb << 10) + (wid << 2) + ej;
        dst[off] = hp;
        if (l == 1) rec[(t << 16) + off] = hp;
      }
      grid_barrier(barp, (unsigned)(2 * t + l + 1), wid, tid);
    }
  }
}

// ---------- FC: out[8192,1024] = rec @ Wfc^T + b_fc (split-bf16 MFMA) ----------
__global__ __launch_bounds__(256) void fc_kernel(
    const unsigned* __restrict__ rec, const unsigned* __restrict__ wfc,
    const float* __restrict__ bfc, float* __restrict__ out) {
  __shared__ unsigned a_lds[128 * 36];
  __shared__ unsigned w_lds[128 * 36];
  const int tid = threadIdx.x;
  const int wave = tid >> 6;
  const int lane = tid & 63;
  const int q = lane >> 4;
  const int m16 = lane & 15;
  const int m0 = (blockIdx.x >> 3) << 7;
  const int n0 = (blockIdx.x & 7) << 7;
  const f32x4 fzero = {0.0f, 0.0f, 0.0f, 0.0f};

  f32x4 acc[2][8];
  for (int mt = 0; mt < 2; ++mt)
    for (int nt = 0; nt < 8; ++nt) acc[mt][nt] = fzero;

  for (int kc = 0; kc < 32; ++kc) {
    __syncthreads();
    #pragma unroll
    for (int i = 0; i < 4; ++i) {
      int c = (i << 8) + tid;
      int r = c >> 3;
      int cc = (c & 7) << 2;
      *(uint4*)(a_lds + r * 36 + cc) = *(const uint4*)(rec + ((m0 + r) << 10) + (kc << 5) + cc);
      *(uint4*)(w_lds + r * 36 + cc) = *(const uint4*)(wfc + ((n0 + r) << 10) + (kc << 5) + cc);
    }
    __syncthreads();

    bf16x8 ahi[2], alo[2];
    #pragma unroll
    for (int mt = 0; mt < 2; ++mt) {
      int arow = (wave << 5) + (mt << 4) + m16;
      uint4 a0 = *(const uint4*)(a_lds + arow * 36 + (q << 3));
      uint4 a1 = *(const uint4*)(a_lds + arow * 36 + (q << 3) + 4);
      unpack2(a0, a1, ahi[mt], alo[mt]);
    }
    #pragma unroll
    for (int nt = 0; nt < 8; ++nt) {
      int wrow = (nt << 4) + m16;
      uint4 b0 = *(const uint4*)(w_lds + wrow * 36 + (q << 3));
      uint4 b1 = *(const uint4*)(w_lds + wrow * 36 + (q << 3) + 4);
      bf16x8 bhi, blo;
      unpack2(b0, b1, bhi, blo);
      #pragma unroll
      for (int mt = 0; mt < 2; ++mt) {
        acc[mt][nt] = __builtin_amdgcn_mfma_f32_16x16x32_bf16(ahi[mt], bhi, acc[mt][nt], 0, 0, 0);
        acc[mt][nt] = __builtin_amdgcn_mfma_f32_16x16x32_bf16(ahi[mt], blo, acc[mt][nt], 0, 0, 0);
        acc[mt][nt] = __builtin_amdgcn_mfma_f32_16x16x32_bf16(alo[mt], bhi, acc[mt][nt], 0, 0, 0);
      }
    }
  }
  #pragma unroll
  for (int mt = 0; mt < 2; ++mt)
    #pragma unroll
    for (int nt = 0; nt < 8; ++nt) {
      int n = n0 + (nt << 4) + m16;
      float bv = bfc[n];
      #pragma unroll
      for (int r2 = 0; r2 < 4; ++r2) {
        int m = m0 + (wave << 5) + (mt << 4) + (q << 2) + r2;
        out[(m << 10) + n] = acc[mt][nt][r2] + bv;
      }
    }
}

// ---------- launch ----------
extern "C" void kernel_launch(void* const* d_in, const int* in_sizes, int n_in,
                              void* d_out, int out_size, void* d_ws, size_t ws_size,
                              hipStream_t stream) {
  const float* h_in = (const float*)d_in[0];
  const float* W_ih = (const float*)d_in[1];
  const float* W_hh = (const float*)d_in[2];
  const float* b_ih = (const float*)d_in[3];
  const float* b_hh = (const float*)d_in[4];
  const float* W_fc = (const float*)d_in[5];
  const float* b_fc = (const float*)d_in[6];
  (void)in_sizes; (void)n_in; (void)out_size; (void)ws_size;

  char* ws = (char*)d_ws;
  unsigned* wreg  = (unsigned*)(ws + 0);          // 64 MB: [256][8][2][8][64][8]
  unsigned* wfc   = (unsigned*)(ws + 67108864);   // 4 MB
  unsigned* hbase = (unsigned*)(ws + 71303168);   // 1 MB: hb[2][2] of 256 KB
  unsigned* hzero = (unsigned*)(ws + 72351744);   // 256 KB, stays zero (layer-1 init hidden)
  unsigned* barp  = (unsigned*)(ws + 72613888);   // 2 KB: [0]=gen, [64+wid]=arrival flags
  unsigned* rec   = (unsigned*)(ws + 72616192);   // 32 MB: [128][64][1024] packed
  float*    out   = (float*)d_out;

  // zero: hb[0][1] (layer-0 init hidden), hzero + barp (contiguous)
  (void)hipMemsetAsync(ws + 71303168 + 262144, 0, 262144, stream);
  (void)hipMemsetAsync(ws + 72351744, 0, 262144 + 2304, stream);

  prep_kernel<<<dim3(8736), dim3(256), 0, stream>>>(W_ih, W_hh, W_fc, h_in,
                                                    wreg, wfc, hbase + 196608);

  lstm_main<<<dim3(NBLK), dim3(512), 0, stream>>>(wreg, hbase, hzero, rec, b_ih, b_hh, barp);

  fc_kernel<<<dim3(512), dim3(256), 0, stream>>>(rec, wfc, b_fc, out);
}

// Round 8
// 2390.486 us; speedup vs baseline: 9.8047x; 1.9838x over previous
//
#include <hip/hip_runtime.h>

typedef __attribute__((ext_vector_type(8))) short bf16x8;
typedef __attribute__((ext_vector_type(4))) float f32x4;

#define NBLK 256

typedef __attribute__((address_space(3))) unsigned lds_u;
typedef __attribute__((address_space(1))) const unsigned glb_u;

// ---------- helpers ----------
__device__ __forceinline__ unsigned short f2bf(float f) {
  unsigned u = __float_as_uint(f);
  unsigned r = u + 0x7fffu + ((u >> 16) & 1u);   // RNE
  return (unsigned short)(r >> 16);
}
__device__ __forceinline__ float bf2f(unsigned short h) {
  return __uint_as_float(((unsigned)h) << 16);
}
// packed = (hi_bits<<16) | lo_bits ; hi+lo reconstructs f to ~2^-16 rel
__device__ __forceinline__ unsigned pack_split(float f) {
  unsigned short hi = f2bf(f);
  float res = f - bf2f(hi);
  unsigned short lo = f2bf(res);
  return (((unsigned)hi) << 16) | (unsigned)lo;
}
// 8 packed elems (2x uint4) -> hi-frag / lo-frag (8 bf16 each)
__device__ __forceinline__ void unpack2(uint4 a0, uint4 a1, bf16x8& hi, bf16x8& lo) {
  union { bf16x8 v; unsigned u[4]; } H, L;
  H.u[0] = (a0.x >> 16) | (a0.y & 0xffff0000u);
  L.u[0] = (a0.x & 0xffffu) | (a0.y << 16);
  H.u[1] = (a0.z >> 16) | (a0.w & 0xffff0000u);
  L.u[1] = (a0.z & 0xffffu) | (a0.w << 16);
  H.u[2] = (a1.x >> 16) | (a1.y & 0xffff0000u);
  L.u[2] = (a1.x & 0xffffu) | (a1.y << 16);
  H.u[3] = (a1.z >> 16) | (a1.w & 0xffff0000u);
  L.u[3] = (a1.z & 0xffffu) | (a1.w << 16);
  hi = H.v; lo = L.v;
}
__device__ __forceinline__ float sigm(float x) { return 1.0f / (1.0f + __expf(-x)); }
__device__ __forceinline__ float tanh_f(float x) { return 1.0f - 2.0f / (__expf(2.0f * x) + 1.0f); }

// ---------- prep: pack weights into per-(WG,wave,layer,ktile) register-load layout ----------
// wreg[wg=256][wave=8][l=2][kt=8][lane=64][e=8] packed dwords.
// For (wg,wave,l,kt,lane,e): n=lane&15, q=lane>>4, g=n>>2, jj=n&3,
//   col = g*1024 + wg*4 + jj,  k = wave*256 + kt*32 + q*8 + e  (k<1024 -> W_ih, else W_hh)
__global__ __launch_bounds__(256) void prep_kernel(
    const float* __restrict__ wih, const float* __restrict__ whh,
    const float* __restrict__ wfc_in, const float* __restrict__ hin,
    unsigned* __restrict__ wreg, unsigned* __restrict__ wfc, unsigned* __restrict__ xinit) {
  for (int e0 = 0; e0 < 8; ++e0) {
    unsigned idx = blockIdx.x * 2048u + (unsigned)e0 * 256u + threadIdx.x;
    if (idx < 16777216u) {
      unsigned wg   = idx >> 16;
      unsigned r    = idx & 65535u;
      unsigned wv   = r >> 13;
      unsigned r2   = r & 8191u;
      unsigned l    = r2 >> 12;
      unsigned r3   = r2 & 4095u;
      unsigned kt   = r3 >> 9;
      unsigned r4   = r3 & 511u;
      unsigned lane = r4 >> 3;
      unsigned e    = r4 & 7u;
      unsigned n = lane & 15u, q = lane >> 4;
      unsigned g = n >> 2, jj = n & 3u;
      unsigned col = (g << 10) + (wg << 2) + jj;
      unsigned k = (wv << 8) + (kt << 5) + (q << 3) + e;
      float v = (k < 1024u) ? wih[(l << 22) + (col << 10) + k]
                            : whh[(l << 22) + (col << 10) + (k - 1024u)];
      wreg[idx] = pack_split(v);
    } else if (idx < 17825792u) {            // wfc [1024][1024]
      unsigned i2 = idx - 16777216u;
      wfc[i2] = pack_split(wfc_in[i2]);
    } else if (idx < 17891328u) {            // x_init packed
      unsigned i3 = idx - 17825792u;
      xinit[i3] = pack_split(hin[i3]);
    }
  }
}

// ---------- distributed grid barrier, FENCE-FREE ----------
// Data is published via agent-scope atomic (write-through) stores to fresh
// addresses, so no L2 invalidate/writeback is needed. Ordering: EW atomic
// stores -> __syncthreads (drains vmcnt: stores acked at coherence point)
// -> relaxed flag store -> block0 aggregates -> relaxed gen store -> spinners.
__device__ __forceinline__ void grid_barrier(unsigned* barp, unsigned g,
                                             int wid, int tid) {
  __syncthreads();
  if (wid == 0) {
    if (tid > 0 && tid < NBLK) {
      while (__hip_atomic_load(&barp[64 + tid], __ATOMIC_RELAXED,
                               __HIP_MEMORY_SCOPE_AGENT) < g) {
        __builtin_amdgcn_s_sleep(1);
      }
    }
    __syncthreads();
    if (tid == 0) {
      __hip_atomic_store(&barp[0], g, __ATOMIC_RELAXED, __HIP_MEMORY_SCOPE_AGENT);
    }
  } else {
    if (tid == 0) {
      __hip_atomic_store(&barp[64 + wid], g, __ATOMIC_RELAXED, __HIP_MEMORY_SCOPE_AGENT);
      while (__hip_atomic_load(&barp[0], __ATOMIC_RELAXED,
                               __HIP_MEMORY_SCOPE_AGENT) < g) {
        __builtin_amdgcn_s_sleep(2);
      }
    }
  }
  __syncthreads();
}

// ---------- main persistent LSTM ----------
// Weights in regs; A staged via async global_load_lds (double-buffered, per-wave
// LDS region); h published to per-phase FRESH slabs (h0buf[t] / rec[t]) via
// agent atomic stores => no per-phase cache fences.
__global__ __launch_bounds__(512, 1) void lstm_main(
    const unsigned* __restrict__ wreg,
    unsigned* __restrict__ h0buf,      // [128][64][1024] (aliases wreg lower half)
    const unsigned* __restrict__ xinit,
    const unsigned* __restrict__ hzero,
    unsigned* __restrict__ rec,        // [128][64][1024] = h1 history
    const float* __restrict__ bih, const float* __restrict__ bhh,
    unsigned* __restrict__ barp) {
  __shared__ unsigned lds_stage[8 * 4096];  // 128 KB: per wave 16 KB (2 bufs x 8 KB)

  const int tid = threadIdx.x;
  const int wid = blockIdx.x;
  const int wave = tid >> 6;
  const int lane = tid & 63;
  const int q = lane >> 4;
  const int m16 = lane & 15;

  // ---- load this wave's weight slice into registers, then pin ----
  bf16x8 whi[2][8], wlo[2][8];
  {
    const unsigned* wb = wreg + ((size_t)wid << 16) + ((size_t)wave << 13) + (lane << 3);
    #pragma unroll
    for (int l = 0; l < 2; ++l)
      #pragma unroll
      for (int kt = 0; kt < 8; ++kt) {
        const unsigned* p = wb + (l << 12) + (kt << 9);
        uint4 a0 = *(const uint4*)p;
        uint4 a1 = *(const uint4*)(p + 4);
        unpack2(a0, a1, whi[l][kt], wlo[l][kt]);
      }
    #pragma unroll
    for (int l = 0; l < 2; ++l)
      #pragma unroll
      for (int kt = 0; kt < 8; ++kt) {
        asm volatile("" : "+v"(whi[l][kt]), "+v"(wlo[l][kt]));
      }
  }

  // EW thread state (threads 0..255 own (b=tid>>2, jj=tid&3))
  const int eb = tid >> 2;
  const int ej = tid & 3;
  float creg[2] = {0.0f, 0.0f};
  float biasr[2][4] = {{0, 0, 0, 0}, {0, 0, 0, 0}};
  if (tid < 256) {
    #pragma unroll
    for (int l = 0; l < 2; ++l)
      #pragma unroll
      for (int g = 0; g < 4; ++g) {
        int col = (g << 10) + (wid << 2) + ej;
        biasr[l][g] = bih[(l << 12) + col] + bhh[(l << 12) + col];
      }
  }

  // All blocks done reading wreg, then ONE-TIME acquire fence: invalidates the
  // clean L2 copies of the wreg lines that h0buf aliases. After this, every
  // read address is either written-once-then-read (h0buf/rec slabs) or
  // read-only (xinit/hzero) => no further fences needed.
  grid_barrier(barp, 1u, wid, tid);
  __builtin_amdgcn_fence(__ATOMIC_ACQUIRE, "agent");

  const int colb = (wave & 3) << 8;           // wave's 256-dword K-slice
  unsigned* const lds_w = lds_stage + (wave << 12);   // this wave's 16 KB region
  const f32x4 fzero = {0.0f, 0.0f, 0.0f, 0.0f};

  // staging-issue lane geometry: instr i covers slots s=i*64+lane
  const int st_r  = lane >> 3;        // + i*8 per instr
  const int st_cs = lane & 7;

  for (int t = 0; t < 128; ++t) {
    #pragma unroll
    for (int l = 0; l < 2; ++l) {
      const unsigned* xs, * hs;
      unsigned* dst;
      if (l == 0) {
        xs = (t == 0) ? xinit : rec + ((t - 1) << 16);
        hs = (t == 0) ? hzero : h0buf + ((t - 1) << 16);
        dst = h0buf + (t << 16);
      } else {
        xs = h0buf + (t << 16);
        hs = (t == 0) ? hzero : rec + ((t - 1) << 16);
        dst = rec + (t << 16);
      }

      const unsigned* src = ((wave < 4) ? xs : hs) + colb;

      #define ISSUE_CHUNK(kt_, bsel_)                                              \
        {                                                                          \
          _Pragma("unroll")                                                        \
          for (int i = 0; i < 8; ++i) {                                            \
            int r = (i << 3) + st_r;                                               \
            int c = st_cs ^ (r & 7);                                               \
            const unsigned* gp = src + (r << 10) + ((kt_) << 5) + (c << 2);        \
            unsigned* lp = lds_w + ((bsel_) << 11) + (i << 8);                     \
            __builtin_amdgcn_global_load_lds((glb_u*)gp, (lds_u*)lp, 16, 0, 0);    \
          }                                                                        \
        }

      f32x4 acc[4];
      #pragma unroll
      for (int mt = 0; mt < 4; ++mt) acc[mt] = fzero;

      ISSUE_CHUNK(0, 0)
      ISSUE_CHUNK(1, 1)

      #pragma unroll
      for (int kt = 0; kt < 8; ++kt) {
        const int bsel = kt & 1;
        if (kt < 7) {
          asm volatile("s_waitcnt vmcnt(8)" ::: "memory");
        } else {
          asm volatile("s_waitcnt vmcnt(0)" ::: "memory");
        }
        const unsigned* bufb = lds_w + (bsel << 11);
        bf16x8 ahi[4], alo[4];
        #pragma unroll
        for (int mt = 0; mt < 4; ++mt) {
          int row = (mt << 4) + m16;
          const unsigned* base = bufb + (row << 5);
          uint4 a0 = *(const uint4*)(base + ((((q << 1)    ) ^ (row & 7)) << 2));
          uint4 a1 = *(const uint4*)(base + ((((q << 1) | 1) ^ (row & 7)) << 2));
          unpack2(a0, a1, ahi[mt], alo[mt]);
        }
        asm volatile("s_waitcnt lgkmcnt(0)" ::: "memory");
        if (kt < 6) ISSUE_CHUNK(kt + 2, bsel)
        #pragma unroll
        for (int mt = 0; mt < 4; ++mt) {
          acc[mt] = __builtin_amdgcn_mfma_f32_16x16x32_bf16(ahi[mt], whi[l][kt], acc[mt], 0, 0, 0);
          acc[mt] = __builtin_amdgcn_mfma_f32_16x16x32_bf16(ahi[mt], wlo[l][kt], acc[mt], 0, 0, 0);
          acc[mt] = __builtin_amdgcn_mfma_f32_16x16x32_bf16(alo[mt], whi[l][kt], acc[mt], 0, 0, 0);
        }
      }
      #undef ISSUE_CHUNK

      // partials -> this wave's own buf0 region (4352 B < 8 KB; chunks consumed)
      {
        float* lds_pw = (float*)lds_w;
        #pragma unroll
        for (int mt = 0; mt < 4; ++mt)
          #pragma unroll
          for (int r = 0; r < 4; ++r) {
            int m = (mt << 4) + (q << 2) + r;
            lds_pw[m * 17 + m16] = acc[mt][r];
          }
      }
      __syncthreads();

      // reduce across 8 waves + elementwise; publish h via agent atomic store
      if (tid < 256) {
        float g4[4];
        #pragma unroll
        for (int g = 0; g < 4; ++g) {
          float s = biasr[l][g];
          #pragma unroll
          for (int w = 0; w < 8; ++w)
            s += ((const float*)(lds_stage + (w << 12)))[eb * 17 + (g << 2) + ej];
          g4[g] = s;
        }
        float ig = sigm(g4[0]);
        float fg = sigm(g4[1]);
        float gv = tanh_f(g4[2]);
        float og = sigm(g4[3]);
        float cn = fg * creg[l] + ig * gv;
        float hn = og * tanh_f(cn);
        creg[l] = cn;
        unsigned hp = pack_split(hn);
        int off = (eb << 10) + (wid << 2) + ej;
        __hip_atomic_store(&dst[off], hp, __ATOMIC_RELAXED, __HIP_MEMORY_SCOPE_AGENT);
      }
      grid_barrier(barp, (unsigned)(2 * t + l + 2), wid, tid);
    }
  }
}

// ---------- FC: out[8192,1024] = rec @ Wfc^T + b_fc (split-bf16 MFMA) ----------
__global__ __launch_bounds__(256) void fc_kernel(
    const unsigned* __restrict__ rec, const unsigned* __restrict__ wfc,
    const float* __restrict__ bfc, float* __restrict__ out) {
  __shared__ unsigned a_lds[128 * 36];
  __shared__ unsigned w_lds[128 * 36];
  const int tid = threadIdx.x;
  const int wave = tid >> 6;
  const int lane = tid & 63;
  const int q = lane >> 4;
  const int m16 = lane & 15;
  const int m0 = (blockIdx.x >> 3) << 7;
  const int n0 = (blockIdx.x & 7) << 7;
  const f32x4 fzero = {0.0f, 0.0f, 0.0f, 0.0f};

  f32x4 acc[2][8];
  for (int mt = 0; mt < 2; ++mt)
    for (int nt = 0; nt < 8; ++nt) acc[mt][nt] = fzero;

  for (int kc = 0; kc < 32; ++kc) {
    __syncthreads();
    #pragma unroll
    for (int i = 0; i < 4; ++i) {
      int c = (i << 8) + tid;
      int r = c >> 3;
      int cc = (c & 7) << 2;
      *(uint4*)(a_lds + r * 36 + cc) = *(const uint4*)(rec + ((m0 + r) << 10) + (kc << 5) + cc);
      *(uint4*)(w_lds + r * 36 + cc) = *(const uint4*)(wfc + ((n0 + r) << 10) + (kc << 5) + cc);
    }
    __syncthreads();

    bf16x8 ahi[2], alo[2];
    #pragma unroll
    for (int mt = 0; mt < 2; ++mt) {
      int arow = (wave << 5) + (mt << 4) + m16;
      uint4 a0 = *(const uint4*)(a_lds + arow * 36 + (q << 3));
      uint4 a1 = *(const uint4*)(a_lds + arow * 36 + (q << 3) + 4);
      unpack2(a0, a1, ahi[mt], alo[mt]);
    }
    #pragma unroll
    for (int nt = 0; nt < 8; ++nt) {
      int wrow = (nt << 4) + m16;
      uint4 b0 = *(const uint4*)(w_lds + wrow * 36 + (q << 3));
      uint4 b1 = *(const uint4*)(w_lds + wrow * 36 + (q << 3) + 4);
      bf16x8 bhi, blo;
      unpack2(b0, b1, bhi, blo);
      #pragma unroll
      for (int mt = 0; mt < 2; ++mt) {
        acc[mt][nt] = __builtin_amdgcn_mfma_f32_16x16x32_bf16(ahi[mt], bhi, acc[mt][nt], 0, 0, 0);
        acc[mt][nt] = __builtin_amdgcn_mfma_f32_16x16x32_bf16(ahi[mt], blo, acc[mt][nt], 0, 0, 0);
        acc[mt][nt] = __builtin_amdgcn_mfma_f32_16x16x32_bf16(alo[mt], bhi, acc[mt][nt], 0, 0, 0);
      }
    }
  }
  #pragma unroll
  for (int mt = 0; mt < 2; ++mt)
    #pragma unroll
    for (int nt = 0; nt < 8; ++nt) {
      int n = n0 + (nt << 4) + m16;
      float bv = bfc[n];
      #pragma unroll
      for (int r2 = 0; r2 < 4; ++r2) {
        int m = m0 + (wave << 5) + (mt << 4) + (q << 2) + r2;
        out[(m << 10) + n] = acc[mt][nt][r2] + bv;
      }
    }
}

// ---------- launch ----------
extern "C" void kernel_launch(void* const* d_in, const int* in_sizes, int n_in,
                              void* d_out, int out_size, void* d_ws, size_t ws_size,
                              hipStream_t stream) {
  const float* h_in = (const float*)d_in[0];
  const float* W_ih = (const float*)d_in[1];
  const float* W_hh = (const float*)d_in[2];
  const float* b_ih = (const float*)d_in[3];
  const float* b_hh = (const float*)d_in[4];
  const float* W_fc = (const float*)d_in[5];
  const float* b_fc = (const float*)d_in[6];
  (void)in_sizes; (void)n_in; (void)out_size; (void)ws_size;

  char* ws = (char*)d_ws;
  unsigned* wreg  = (unsigned*)(ws + 0);          // 64 MB: [256][8][2][8][64][8]
  unsigned* h0buf = (unsigned*)(ws + 0);          // 32 MB, ALIASES wreg lower half
                                                  // (wreg dead after reg-load + barrier + fence)
  unsigned* wfc   = (unsigned*)(ws + 67108864);   // 4 MB
  unsigned* xinit = (unsigned*)(ws + 71303168);   // 256 KB (packed x_init)
  unsigned* hzero = (unsigned*)(ws + 71565312);   // 256 KB, stays zero
  unsigned* barp  = (unsigned*)(ws + 71827456);   // 4 KB: [0]=gen, [64+wid]=flags
  unsigned* rec   = (unsigned*)(ws + 72616192);   // 32 MB: [128][64][1024] = h1 history
  float*    out   = (float*)d_out;

  // zero: hzero + barp (contiguous)
  (void)hipMemsetAsync(ws + 71565312, 0, 262144 + 266240, stream);

  prep_kernel<<<dim3(8736), dim3(256), 0, stream>>>(W_ih, W_hh, W_fc, h_in,
                                                    wreg, wfc, xinit);

  lstm_main<<<dim3(NBLK), dim3(512), 0, stream>>>(wreg, h0buf, xinit, hzero, rec,
                                                  b_ih, b_hh, barp);

  fc_kernel<<<dim3(512), dim3(256), 0, stream>>>(rec, wfc, b_fc, out);
}